// Round 7
// baseline (153.039 us; speedup 1.0000x reference)
//
#include <hip/hip_runtime.h>
#include <stdint.h>

// MemoryEfficientBSpline: out[b,o,p] = sum_i sum_g hat_g(nx[b,i,p]) * coef[b,o,i,g]
// hat_g(nx) = max(0, 1 - |nx - g|),  nx = clamp(x*2.5+2.5, 0, 5) in [0,5], G=6.
// Batched GEMM M=64(o) x N=36864(p) x K=384(i*G) via mfma_f32_16x16x32_f16.
//
// v8 = v7 with the spill hazard removed. v7's NaN: __launch_bounds__(256,6)
// capped the unified reg budget at ~85/wave but demand is ~100 (76 VGPR + 24
// AGPR acc) -> allocator spilled. Spills are fatal here: (a) LLVM treats asm
// global_load dests as ready right after the asm stmt, so a scratch spill
// stores the register BEFORE the load lands (garbage -> NaN); (b) scratch ops
// bump vmcnt, corrupting the hand-counted vmcnt(24). Fix: (256,4) = 128-reg
// budget, no spill; achieved occupancy = min(LDS 6 blocks, regs ~5 blocks).
// Structure unchanged from v7:
//   - o-split: each block does 32 of 64 output channels; coef tile 25KB ->
//     occupancy ceiling rises from v6's 3 blocks/CU to ~5-6.
//   - volatile-asm sink-proof x double-buffer, vmcnt(24) cross-chunk pipeline,
//     coef staged to LDS once, ONE barrier, plain epilogue stores.
//   - o-half pairs of one x-tile dispatched 8 bids apart -> same XCD L2.

typedef __fp16 half8_t __attribute__((ext_vector_type(8)));
typedef __fp16 half2_t __attribute__((ext_vector_type(2)));
typedef float f32x4 __attribute__((ext_vector_type(4)));

#define NBATCH 8
#define OD 64
#define OB 32              // o-rows per block (o-split)
#define ID 64
#define PIX 36864          // 192*192
#define NG 6
#define PT 192             // pixels per block tile (4 waves x 48)
#define KI 16              // i per chunk
#define NCHUNK 4           // 4 * 16 = 64 = ID
#define KC (KI * NG)       // 96 k-values per chunk (g-major: k = g*16 + iof)
#define AROW 392           // f16 row stride: 384 used + 8 pad (bank spread)
#define PTILES (PIX / PT)  // 192 p-tiles per batch

// Issue 24 sink-proof loads for chunk cc into dst[24] (quarter-wave 64B coalesced).
// One asm stmt per j: 3 loads, early-clobber dests so none aliases the addr pair.
#define LOADCHUNK(dst, cc)                                                      \
  do {                                                                          \
    _Pragma("unroll") for (int j = 0; j < 8; ++j) {                             \
      const float* a_ = xb + (size_t)((cc) * KI + j) * PIX;                     \
      asm volatile("global_load_dword %0, %3, off\n\t"                          \
                   "global_load_dword %1, %3, off offset:64\n\t"                \
                   "global_load_dword %2, %3, off offset:128"                   \
                   : "=&v"(dst[j * 3 + 0]), "=&v"(dst[j * 3 + 1]),              \
                     "=&v"(dst[j * 3 + 2])                                      \
                   : "v"(a_));                                                  \
    }                                                                           \
    __builtin_amdgcn_sched_barrier(0);                                          \
  } while (0)

#define VMWAIT(n)                                                               \
  do {                                                                          \
    asm volatile("s_waitcnt vmcnt(" #n ")" ::: "memory");                       \
    __builtin_amdgcn_sched_barrier(0);                                          \
  } while (0)

__global__ __launch_bounds__(256, 4)
void kan_mfma(const float* __restrict__ x, const float* __restrict__ coef,
              float* __restrict__ out) {
  const int t = threadIdx.x;
  const int lane = t & 63;
  const int wave = t >> 6;      // 0..3, owns p sub-range [wave*48, wave*48+48)
  const int q8 = lane >> 4;     // 0..3
  const int col = lane & 15;

  // bid -> (tile, ohalf): the two o-halves of one x-tile are 8 bids apart
  // (same XCD under round-robin dispatch -> shared x-tile in one L2).
  const int bid = blockIdx.x;
  const int tile = (bid & 7) | ((bid >> 4) << 3);
  const int ohalf = (bid >> 3) & 1;
  const int b = tile / PTILES;   // same-b tiles contiguous -> coef L2 locality
  const int ptile = tile % PTILES;
  const int p0 = ptile * PT;
  const int o0 = ohalf * OB;

  __shared__ __fp16 A_lds[OB][AROW] __attribute__((aligned(16)));

  const int iof0 = (q8 & 1) * 8;  // which 8 i's this lane's fragment covers
  const int ghalf = q8 >> 1;      // g = 2*ks + ghalf
  const float* xb = x + (size_t)b * ID * PIX + p0 + wave * 48 + col
                      + (size_t)iof0 * PIX;

  float xA[24], xB[24];

  // ---- chunk 0's loads issue FIRST: latency hides under coef staging ----
  LOADCHUNK(xA, 0);

  // ---- stage this block's 32 coef rows as f16, g-major per 16-i chunk ----
  // thread t: o_local = t>>3, sub = t&7 -> chunk c = sub>>1, iof-half = sub&1
  // (48 contiguous f32 of coef[b][o0+o_local][c*16 + half*8 ..][g] each)
  {
    const int ol = t >> 3;
    const int sub = t & 7;
    const int c = sub >> 1;
    const int half = sub & 1;
    const float* crow = coef + (size_t)b * (OD * ID * NG)
                        + (size_t)(o0 + ol) * (ID * NG) + c * KC + half * 48;
    __fp16* arow = &A_lds[ol][c * KC];
#pragma unroll
    for (int blk = 0; blk < 4; ++blk) {  // 2 iof's per blk: src r = iof_l*6+g, r+6
      const int bb = half * 4 + blk;     // iof pair index 0..7 within chunk
      f32x4 va = ((const f32x4*)crow)[blk * 3 + 0];
      f32x4 vb = ((const f32x4*)crow)[blk * 3 + 1];
      f32x4 vc = ((const f32x4*)crow)[blk * 3 + 2];
      const float lo[NG] = {va[0], va[1], va[2], va[3], vb[0], vb[1]};
      const float hi[NG] = {vb[2], vb[3], vc[0], vc[1], vc[2], vc[3]};
#pragma unroll
      for (int g = 0; g < NG; ++g) {
        half2_t h2 = __builtin_amdgcn_cvt_pkrtz(lo[g], hi[g]);
        *(half2_t*)&arow[g * KI + bb * 2] = h2;  // 4B-aligned b32 write
      }
    }
  }

  f32x4 acc[2][3];
#pragma unroll
  for (int i = 0; i < 2; ++i)
#pragma unroll
    for (int j = 0; j < 3; ++j)
      acc[i][j] = (f32x4){0.f, 0.f, 0.f, 0.f};

  __syncthreads();  // the ONLY barrier (its drain covers chunk 0's loads)

#pragma unroll
  for (int c = 0; c < NCHUNK; ++c) {
    float* xc = (c & 1) ? xB : xA;  // static after full unroll
    float* xn = (c & 1) ? xA : xB;

    // ---- issue chunk c+1's 24 loads; they stay in flight through compute ----
    if (c + 1 < NCHUNK) {
      LOADCHUNK(xn, c + 1);
      VMWAIT(24);  // >=24 retired in-order => all of chunk c landed
    } else {
      VMWAIT(0);
    }

    // ---- nx for my 24 (p, i) pairs ----
    float nxv[3][8];
#pragma unroll
    for (int j = 0; j < 8; ++j) {
#pragma unroll
      for (int pt = 0; pt < 3; ++pt)
        nxv[pt][j] = fminf(fmaxf(xc[j * 3 + pt] * 2.5f + 2.5f, 0.f), 5.f);
    }

#pragma unroll
    for (int ks = 0; ks < 3; ++ks) {
      half8_t af[2];
#pragma unroll
      for (int ot = 0; ot < 2; ++ot)
        af[ot] = *(const half8_t*)&A_lds[ot * 16 + col][c * KC + ks * 32 + q8 * 8];

      const float gf = (float)(2 * ks + ghalf);
#pragma unroll
      for (int pti = 0; pti < 3; ++pti) {
        union { half2_t h2[4]; half8_t v; } bu;
#pragma unroll
        for (int jj = 0; jj < 4; ++jj) {
          float h0 = 1.f - fabsf(nxv[pti][2 * jj] - gf);
          float h1 = 1.f - fabsf(nxv[pti][2 * jj + 1] - gf);
          half2_t h2 = __builtin_amdgcn_cvt_pkrtz(h0, h1);
          bu.h2[jj] = __builtin_elementwise_max(h2, (half2_t)(__fp16)0.f);
        }
#pragma unroll
        for (int ot = 0; ot < 2; ++ot)
          acc[ot][pti] = __builtin_amdgcn_mfma_f32_16x16x32_f16(
              af[ot], bu.v, acc[ot][pti], 0, 0, 0);
      }
    }
  }

  // ---- epilogue: C row = q8*4 + reg, col = lane&15 (plain stores: L2 merges) ----
  float* ob = out + (size_t)b * OD * PIX + p0;
#pragma unroll
  for (int ot = 0; ot < 2; ++ot) {
#pragma unroll
    for (int pti = 0; pti < 3; ++pti) {
      int p = wave * 48 + pti * 16 + col;
#pragma unroll
      for (int r = 0; r < 4; ++r) {
        int o = o0 + ot * 16 + q8 * 4 + r;
        ob[(size_t)o * PIX + p] = acc[ot][pti][r];
      }
    }
  }
}

extern "C" void kernel_launch(void* const* d_in, const int* in_sizes, int n_in,
                              void* d_out, int out_size, void* d_ws, size_t ws_size,
                              hipStream_t stream) {
  const float* x = (const float*)d_in[0];
  const float* coef = (const float*)d_in[1];
  float* out = (float*)d_out;
  dim3 grid(NBATCH * PTILES * 2);
  dim3 block(256);
  hipLaunchKernelGGL(kan_mfma, grid, block, 0, stream, x, coef, out);
}

// Round 8
// 144.207 us; speedup vs baseline: 1.0612x; 1.0612x over previous
//
#include <hip/hip_runtime.h>
#include <stdint.h>

// MemoryEfficientBSpline: out[b,o,p] = sum_i sum_g hat_g(nx[b,i,p]) * coef[b,o,i,g]
// hat_g(nx) = max(0, 1 - |nx - g|),  nx = clamp(x*2.5+2.5, 0, 5) in [0,5], G=6.
// Batched GEMM M=64(o) x N=36864(p) x K=384(i*G) via mfma_f32_16x16x32_f16.
//
// v9: attack VMEM-instruction (TA) throughput. Evidence: v6 vs v8 showed a
// constant 42-43us wait unaffected by +56% occupancy (not latency) with HBM/
// L2/LDS all <30% of ceiling; the only constant saturable resource is VMEM
// instruction throughput (24 narrow 2-line global_load_dword per wave-chunk,
// 2x lane-duplicated). Changes vs v6 (best, 60.6us):
//  - x staged to LDS via 3 fully-coalesced global_load_dwordx4 per thread per
//    chunk (1KB/wave-instr, 8x fewer x VMEM instrs), double-buffered nx tile,
//    ONE barrier per chunk. Loads for chunk c+1 issue (volatile asm, sink-
//    proof) before chunk c's compute; vmcnt(0)+write after -> latency hidden.
//  - clamp/scale on the write side (12 vals/thread vs 24/lane).
//  - packed-f16 hat math: per k-pair {v_pk_sub, v_and, v_pk_sub, v_pk_max} =
//    4 VALU instead of 8 f32 ops (VALU was ~25% of critical path per v8 A/B).
//  - keeps: coef-once LDS (g-major), full 64-o per block (each bu feeds 4
//    MFMAs -- v8 proved halving this is -20%), plain epilogue stores.

typedef __fp16 half8_t __attribute__((ext_vector_type(8)));
typedef __fp16 half2_t __attribute__((ext_vector_type(2)));
typedef float f32x4 __attribute__((ext_vector_type(4)));

#define NBATCH 8
#define OD 64
#define ID 64
#define PIX 36864          // 192*192
#define NG 6
#define PT 192             // pixels per block tile (4 waves x 48)
#define KI 16              // i per chunk
#define NCHUNK 4           // 4 * 16 = 64 = ID
#define KC (KI * NG)       // 96 k-values per chunk (g-major: k = g*16 + iof)
#define AROW 392           // coef f16 row stride: 384 used + 8 pad
#define XROW 200           // nx f32 row stride: 192 used + 8 pad (2-way banks)
#define PTILES (PIX / PT)  // 192 p-tiles per batch

// 3 sink-proof coalesced dwordx4 loads: thread t covers x[chunk row trow]
// [p = (t&15)*12 .. +11]. One shared addr, offsets 0/16/32, early-clobber.
#define LOADX(dst, cc)                                                          \
  do {                                                                          \
    const float* a_ = xstage + (size_t)((cc) * KI + trow) * PIX;                \
    asm volatile("global_load_dwordx4 %0, %3, off\n\t"                          \
                 "global_load_dwordx4 %1, %3, off offset:16\n\t"                \
                 "global_load_dwordx4 %2, %3, off offset:32"                    \
                 : "=&v"(dst[0]), "=&v"(dst[1]), "=&v"(dst[2])                  \
                 : "v"(a_));                                                    \
    __builtin_amdgcn_sched_barrier(0);                                          \
  } while (0)

#define VMWAIT0                                                                 \
  do {                                                                          \
    asm volatile("s_waitcnt vmcnt(0)" ::: "memory");                            \
    __builtin_amdgcn_sched_barrier(0);                                          \
  } while (0)

__global__ __launch_bounds__(256, 2)
void kan_mfma(const float* __restrict__ x, const float* __restrict__ coef,
              float* __restrict__ out) {
  const int t = threadIdx.x;
  const int lane = t & 63;
  const int wave = t >> 6;      // 0..3, owns p sub-range [wave*48, wave*48+48)
  const int q8 = lane >> 4;     // 0..3
  const int col = lane & 15;

  const int bid = blockIdx.x;
  const int b = bid / PTILES;   // same-b blocks contiguous -> coef L2 locality
  const int ptile = bid % PTILES;
  const int p0 = ptile * PT;

  __shared__ __fp16 A_lds[OD][AROW] __attribute__((aligned(16)));
  __shared__ float nx_lds[2][KI][XROW] __attribute__((aligned(16)));

  const int iof0 = (q8 & 1) * 8;  // which 8 i's this lane's fragment covers
  const int ghalf = q8 >> 1;      // g = 2*ks + ghalf
  const int trow = t >> 4;        // staging row 0..15 (chunk-local i)
  const int tc12 = (t & 15) * 12; // staging p-offset (12 f32 per thread)
  const float* xstage = x + (size_t)b * ID * PIX + p0 + tc12;

  f32x4 xr[3];

  // ---- chunk 0's loads issue FIRST: latency hides under coef staging ----
  LOADX(xr, 0);

  // ---- stage ALL coef as f16, g-major per 16-i chunk: A[o][c*96 + g*16 + iof] ----
  {
    const int o = t >> 2;
    const int c = t & 3;
    const float* crow = coef + (size_t)b * (OD * ID * NG) + o * (ID * NG) + c * KC;
    __fp16* arow = &A_lds[o][c * KC];
#pragma unroll
    for (int blk = 0; blk < 8; ++blk) {  // 2 iof's per blk: src r = iof*6+g, r+6
      f32x4 va = ((const f32x4*)crow)[blk * 3 + 0];
      f32x4 vb = ((const f32x4*)crow)[blk * 3 + 1];
      f32x4 vc = ((const f32x4*)crow)[blk * 3 + 2];
      const float lo[NG] = {va[0], va[1], va[2], va[3], vb[0], vb[1]};
      const float hi[NG] = {vb[2], vb[3], vc[0], vc[1], vc[2], vc[3]};
#pragma unroll
      for (int g = 0; g < NG; ++g) {
        half2_t h2 = __builtin_amdgcn_cvt_pkrtz(lo[g], hi[g]);
        *(half2_t*)&arow[g * KI + blk * 2] = h2;  // 4B-aligned b32 write
      }
    }
  }

  f32x4 acc[4][3];
#pragma unroll
  for (int i = 0; i < 4; ++i)
#pragma unroll
    for (int j = 0; j < 3; ++j)
      acc[i][j] = (f32x4){0.f, 0.f, 0.f, 0.f};

  // ---- stage chunk 0 (clamp on write side), then the prologue barrier ----
  VMWAIT0;
#pragma unroll
  for (int r = 0; r < 3; ++r) {
    f32x4 v = xr[r];
#pragma unroll
    for (int e = 0; e < 4; ++e)
      v[e] = fminf(fmaxf(v[e] * 2.5f + 2.5f, 0.f), 5.f);
    *(f32x4*)&nx_lds[0][trow][tc12 + r * 4] = v;
  }
  __syncthreads();

  const int wp = wave * 48 + col;
  const half2_t one2 = {(__fp16)1.f, (__fp16)1.f};
  const half2_t zero2 = {(__fp16)0.f, (__fp16)0.f};

#pragma unroll
  for (int c = 0; c < NCHUNK; ++c) {
    // ---- issue chunk c+1's 3 wide loads; in flight through this compute ----
    if (c + 1 < NCHUNK) LOADX(xr, c + 1);

    // ---- my 12 nx pairs for this chunk (rows iof0+2jj, iof0+2jj+1) ----
    half2_t nx2[3][4];
#pragma unroll
    for (int pti = 0; pti < 3; ++pti) {
#pragma unroll
      for (int jj = 0; jj < 4; ++jj) {
        float lo = nx_lds[c & 1][iof0 + 2 * jj][wp + pti * 16];
        float hi = nx_lds[c & 1][iof0 + 2 * jj + 1][wp + pti * 16];
        nx2[pti][jj] = __builtin_amdgcn_cvt_pkrtz(lo, hi);
      }
    }

#pragma unroll
    for (int ks = 0; ks < 3; ++ks) {
      half8_t af[4];
#pragma unroll
      for (int ot = 0; ot < 4; ++ot)
        af[ot] = *(const half8_t*)&A_lds[ot * 16 + col][c * KC + ks * 32 + q8 * 8];

      const float gf = (float)(2 * ks + ghalf);
      const __fp16 gh = (__fp16)gf;
      const half2_t gf2 = {gh, gh};
#pragma unroll
      for (int pti = 0; pti < 3; ++pti) {
        union { half2_t h2[4]; half8_t v; } bu;
#pragma unroll
        for (int jj = 0; jj < 4; ++jj) {
          half2_t d = nx2[pti][jj] - gf2;                 // v_pk_add_f16
          union { half2_t h; uint32_t u; } du;
          du.h = d;
          du.u &= 0x7FFF7FFFu;                            // packed |.|
          half2_t hh = one2 - du.h;                       // v_pk_add_f16
          bu.h2[jj] = __builtin_elementwise_max(hh, zero2);  // v_pk_max_f16
        }
#pragma unroll
        for (int ot = 0; ot < 4; ++ot)
          acc[ot][pti] = __builtin_amdgcn_mfma_f32_16x16x32_f16(
              af[ot], bu.v, acc[ot][pti], 0, 0, 0);
      }
    }

    // ---- land chunk c+1, clamp, write other buffer, one barrier ----
    if (c + 1 < NCHUNK) {
      VMWAIT0;
#pragma unroll
      for (int r = 0; r < 3; ++r) {
        f32x4 v = xr[r];
#pragma unroll
        for (int e = 0; e < 4; ++e)
          v[e] = fminf(fmaxf(v[e] * 2.5f + 2.5f, 0.f), 5.f);
        *(f32x4*)&nx_lds[(c + 1) & 1][trow][tc12 + r * 4] = v;
      }
      __syncthreads();
    }
  }

  // ---- epilogue: C row = q8*4 + reg, col = lane&15 (plain stores: L2 merges) ----
  float* ob = out + (size_t)b * OD * PIX + p0;
#pragma unroll
  for (int ot = 0; ot < 4; ++ot) {
#pragma unroll
    for (int pti = 0; pti < 3; ++pti) {
      int p = wave * 48 + pti * 16 + col;
#pragma unroll
      for (int r = 0; r < 4; ++r) {
        int o = ot * 16 + q8 * 4 + r;
        ob[(size_t)o * PIX + p] = acc[ot][pti][r];
      }
    }
  }
}

extern "C" void kernel_launch(void* const* d_in, const int* in_sizes, int n_in,
                              void* d_out, int out_size, void* d_ws, size_t ws_size,
                              hipStream_t stream) {
  const float* x = (const float*)d_in[0];
  const float* coef = (const float*)d_in[1];
  float* out = (float*)d_out;
  dim3 grid(NBATCH * PTILES);
  dim3 block(256);
  hipLaunchKernelGGL(kan_mfma, grid, block, 0, stream, x, coef, out);
}